// Round 4
// baseline (2320.417 us; speedup 1.0000x reference)
//
#include <hip/hip_runtime.h>

// SineLSTM R4: revert R3's readlane (SGPR-hazard serialization regressed);
// base = R2 LDS-broadcast, restructured:
//  - h1 fetched ONCE per step, feeds both W_ih2·h1(s) and W_hh1·h1(s) (the
//    g1(s+1) stash): 150 -> 104 fetched elems/wave/step.
//  - ds_read_b128 (float4) broadcasts: 26 LDS instrs instead of 104.
//  - 2 barriers/step steady-state: U-phase = U1(s)[w2] || U2(s-1)[w0] ||
//    out(s-1)[w1];  G-phase = g2(s) + g1(s+1), activations pre-folded
//    (act = 1 - m/(e^{m v}+1), m=2 for g-gate else 1).
//  - predict region (o(s) feeds g1(s+1)) uses a 4-barrier variant, 33 iters.

#define Hh   50
#define G4   200
#define TLEN 1024
#define KP   52      // padded K (weights/h zero-padded to 52 = 13 float4)

extern "C" __global__ __launch_bounds__(256, 2)
void sine_lstm_kernel(const float* __restrict__ x,
                      const float* __restrict__ W_ih1,
                      const float* __restrict__ W_hh1,
                      const float* __restrict__ b_ih1,
                      const float* __restrict__ b_hh1,
                      const float* __restrict__ W_ih2,
                      const float* __restrict__ W_hh2,
                      const float* __restrict__ b_ih2,
                      const float* __restrict__ b_hh2,
                      const float* __restrict__ W_lin,
                      const float* __restrict__ b_lin,
                      const int*   __restrict__ predict_p,
                      float* __restrict__ out,
                      int T)
{
    __shared__ __align__(16) float x_lds[TLEN];
    __shared__ __align__(16) float h1buf[64], h2buf[64], c2buf[64];
    __shared__ __align__(16) float g1[G4], g2[G4];   // PRE-ACTIVATED gates
    __shared__ float o_lds;

    const int tid = threadIdx.x;
    const int b   = blockIdx.x;
    const int predict = *predict_p;
    const int S = T + predict;

    // ---- stage x row (coalesced) ----
    for (int i = tid; i < TLEN; i += 256)
        x_lds[i] = x[(size_t)b * T + i];
    if (tid < 64) { h1buf[tid] = 0.0f; h2buf[tid] = 0.0f; c2buf[tid] = 0.0f; }

    // ---- per-thread weight rows, zero-padded to KP ----
    const int j  = tid;
    const int jw = (j < G4) ? j : (G4 - 1);
    float w1[KP], wi2[KP], wh2[KP];
    const float wih1_j = W_ih1[jw];
    const float b1_j   = b_ih1[jw] + b_hh1[jw];
    const float b2_j   = b_ih2[jw] + b_hh2[jw];
    #pragma unroll
    for (int k = 0; k < Hh; ++k) {
        w1[k]  = W_hh1[jw * Hh + k];
        wi2[k] = W_ih2[jw * Hh + k];
        wh2[k] = W_hh2[jw * Hh + k];
    }
    #pragma unroll
    for (int k = Hh; k < KP; ++k) { w1[k] = 0.0f; wi2[k] = 0.0f; wh2[k] = 0.0f; }
    const float mgate = (jw >= 2 * Hh && jw < 3 * Hh) ? 2.0f : 1.0f;

    const int wv = tid >> 6;
    const int ln = tid & 63;
    const float wlin_l = (ln < Hh) ? W_lin[ln] : 0.0f;
    const float blin   = b_lin[0];

    float c1r = 0.0f;      // c1: VGPR-resident in wave2 lanes<50
    float cp2 = 0.0f;      // wave1's preloaded c2 (one step stale, by design)
    float st  = 0.0f;      // g1-stash W_hh1·h1(i), carried U-phase -> GB

    __syncthreads();
    // prologue: g1(0) = act(b1 + x0*wih1)
    {
        const float v = b1_j + x_lds[0] * wih1_j;
        const float a = 1.0f - mgate * __fdividef(1.0f, __expf(mgate * v) + 1.0f);
        if (j < G4) g1[j] = a;
    }
    __syncthreads();

    const float4* h1q = (const float4*)h1buf;
    const float4* h2q = (const float4*)h2buf;

    int i = 0;
    // ================= teacher region: i = 0 .. T-2 =================
    for (; i < T - 1; ++i) {
        // ---- U-phase ----
        if (wv == 2 && ln < Hh) {            // U1(i): h1(i) from g1(i), c1
            const float iA = g1[ln], fA = g1[ln + Hh], gA = g1[ln + 2*Hh], oA = g1[ln + 3*Hh];
            const float cn = fA * c1r + iA * gA;
            c1r = cn;
            const float th = 1.0f - __fdividef(2.0f, __expf(2.0f * cn) + 1.0f);
            h1buf[ln] = oA * th;
        }
        if (wv == 0 && ln < Hh && i > 0) {   // U2(i-1)
            const float iA = g2[ln], fA = g2[ln + Hh], gA = g2[ln + 2*Hh], oA = g2[ln + 3*Hh];
            const float cn = fA * c2buf[ln] + iA * gA;
            c2buf[ln] = cn;
            const float th = 1.0f - __fdividef(2.0f, __expf(2.0f * cn) + 1.0f);
            h2buf[ln] = oA * th;
        }
        if (wv == 1 && i > 0) {              // out(i-1), redundant compute w/ cp2
            float part = 0.0f;
            if (ln < Hh) {
                const float iA = g2[ln], fA = g2[ln + Hh], gA = g2[ln + 2*Hh], oA = g2[ln + 3*Hh];
                const float cn = fA * cp2 + iA * gA;
                const float th = 1.0f - __fdividef(2.0f, __expf(2.0f * cn) + 1.0f);
                part = (oA * th) * wlin_l;
            }
            #pragma unroll
            for (int off = 32; off > 0; off >>= 1) part += __shfl_down(part, off);
            if (ln == 0) out[(size_t)b * S + (i - 1)] = part + blin;
        }
        __syncthreads();

        // ---- G-phase: g2(i), g1(i+1) ----
        if (wv == 1) cp2 = c2buf[ln];        // preload c2(i-1) for out(i) next U
        float a0=0,a1=0,a2=0,a3=0;           // wi2·h1
        float s0=0,s1=0,s2=0,s3=0;           // w1·h1 (stash)
        float d0=0,d1=0,d2=0,d3=0;           // wh2·h2
        #pragma unroll
        for (int t = 0; t < 13; ++t) {
            const float4 p = h1q[t];
            const float4 q = h2q[t];
            a0 += wi2[4*t+0]*p.x; a1 += wi2[4*t+1]*p.y; a2 += wi2[4*t+2]*p.z; a3 += wi2[4*t+3]*p.w;
            s0 += w1 [4*t+0]*p.x; s1 += w1 [4*t+1]*p.y; s2 += w1 [4*t+2]*p.z; s3 += w1 [4*t+3]*p.w;
            d0 += wh2[4*t+0]*q.x; d1 += wh2[4*t+1]*q.y; d2 += wh2[4*t+2]*q.z; d3 += wh2[4*t+3]*q.w;
        }
        {
            const float v2 = b2_j + ((a0+a2)+(a1+a3)) + ((d0+d2)+(d1+d3));
            const float g2v = 1.0f - mgate * __fdividef(1.0f, __expf(mgate * v2) + 1.0f);
            const float v1 = b1_j + ((s0+s2)+(s1+s3)) + x_lds[i+1] * wih1_j;
            const float g1v = 1.0f - mgate * __fdividef(1.0f, __expf(mgate * v1) + 1.0f);
            if (j < G4) { g2[j] = g2v; g1[j] = g1v; }
        }
        __syncthreads();
    }

    // ================= predict region: i = T-1 .. S-1 =================
    for (; i < S; ++i) {
        // ---- UA: U1(i); first iter also drains U2(T-2), out(T-2) ----
        if (wv == 2 && ln < Hh) {
            const float iA = g1[ln], fA = g1[ln + Hh], gA = g1[ln + 2*Hh], oA = g1[ln + 3*Hh];
            const float cn = fA * c1r + iA * gA;
            c1r = cn;
            const float th = 1.0f - __fdividef(2.0f, __expf(2.0f * cn) + 1.0f);
            h1buf[ln] = oA * th;
        }
        if (i == T - 1) {
            if (wv == 0 && ln < Hh && i > 0) {
                const float iA = g2[ln], fA = g2[ln + Hh], gA = g2[ln + 2*Hh], oA = g2[ln + 3*Hh];
                const float cn = fA * c2buf[ln] + iA * gA;
                c2buf[ln] = cn;
                const float th = 1.0f - __fdividef(2.0f, __expf(2.0f * cn) + 1.0f);
                h2buf[ln] = oA * th;
            }
            if (wv == 1 && i > 0) {
                float part = 0.0f;
                if (ln < Hh) {
                    const float iA = g2[ln], fA = g2[ln + Hh], gA = g2[ln + 2*Hh], oA = g2[ln + 3*Hh];
                    const float cn = fA * cp2 + iA * gA;
                    const float th = 1.0f - __fdividef(2.0f, __expf(2.0f * cn) + 1.0f);
                    part = (oA * th) * wlin_l;
                }
                #pragma unroll
                for (int off = 32; off > 0; off >>= 1) part += __shfl_down(part, off);
                if (ln == 0) out[(size_t)b * S + (i - 1)] = part + blin;
            }
        }
        __syncthreads();

        // ---- GA: g2(i) + stash ----
        if (wv == 1) cp2 = c2buf[ln];        // c2(i-1), stable here
        {
            float a0=0,a1=0,a2=0,a3=0, s0=0,s1=0,s2=0,s3=0, d0=0,d1=0,d2=0,d3=0;
            #pragma unroll
            for (int t = 0; t < 13; ++t) {
                const float4 p = h1q[t];
                const float4 q = h2q[t];
                a0 += wi2[4*t+0]*p.x; a1 += wi2[4*t+1]*p.y; a2 += wi2[4*t+2]*p.z; a3 += wi2[4*t+3]*p.w;
                s0 += w1 [4*t+0]*p.x; s1 += w1 [4*t+1]*p.y; s2 += w1 [4*t+2]*p.z; s3 += w1 [4*t+3]*p.w;
                d0 += wh2[4*t+0]*q.x; d1 += wh2[4*t+1]*q.y; d2 += wh2[4*t+2]*q.z; d3 += wh2[4*t+3]*q.w;
            }
            const float v2 = b2_j + ((a0+a2)+(a1+a3)) + ((d0+d2)+(d1+d3));
            const float g2v = 1.0f - mgate * __fdividef(1.0f, __expf(mgate * v2) + 1.0f);
            if (j < G4) g2[j] = g2v;
            st = (s0+s2)+(s1+s3);
        }
        __syncthreads();

        // ---- UB: U2(i) [w0] + out(i) [w1] ----
        if (wv == 0 && ln < Hh) {
            const float iA = g2[ln], fA = g2[ln + Hh], gA = g2[ln + 2*Hh], oA = g2[ln + 3*Hh];
            const float cn = fA * c2buf[ln] + iA * gA;
            c2buf[ln] = cn;
            const float th = 1.0f - __fdividef(2.0f, __expf(2.0f * cn) + 1.0f);
            h2buf[ln] = oA * th;
        }
        if (wv == 1) {
            float part = 0.0f;
            if (ln < Hh) {
                const float iA = g2[ln], fA = g2[ln + Hh], gA = g2[ln + 2*Hh], oA = g2[ln + 3*Hh];
                const float cn = fA * cp2 + iA * gA;
                const float th = 1.0f - __fdividef(2.0f, __expf(2.0f * cn) + 1.0f);
                part = (oA * th) * wlin_l;
            }
            #pragma unroll
            for (int off = 32; off > 0; off >>= 1) part += __shfl_down(part, off);
            if (ln == 0) {
                const float o = part + blin;
                out[(size_t)b * S + i] = o;
                o_lds = o;
            }
        }
        __syncthreads();

        // ---- GB: g1(i+1) = act(b1 + stash + o(i)*wih1) ----
        if (i + 1 < S) {
            const float v1 = b1_j + st + o_lds * wih1_j;
            const float g1v = 1.0f - mgate * __fdividef(1.0f, __expf(mgate * v1) + 1.0f);
            if (j < G4) g1[j] = g1v;
        }
        __syncthreads();
    }
}

extern "C" void kernel_launch(void* const* d_in, const int* in_sizes, int n_in,
                              void* d_out, int out_size, void* d_ws, size_t ws_size,
                              hipStream_t stream) {
    const float* x      = (const float*)d_in[0];
    const float* W_ih1  = (const float*)d_in[1];
    const float* W_hh1  = (const float*)d_in[2];
    const float* b_ih1  = (const float*)d_in[3];
    const float* b_hh1  = (const float*)d_in[4];
    const float* W_ih2  = (const float*)d_in[5];
    const float* W_hh2  = (const float*)d_in[6];
    const float* b_ih2  = (const float*)d_in[7];
    const float* b_hh2  = (const float*)d_in[8];
    const float* W_lin  = (const float*)d_in[9];
    const float* b_lin  = (const float*)d_in[10];
    const int*   pred   = (const int*)d_in[11];
    float* out = (float*)d_out;

    const int B = 512;
    const int T = in_sizes[0] / B;   // 1024

    dim3 grid(B), block(256);
    hipLaunchKernelGGL(sine_lstm_kernel, grid, block, 0, stream,
                       x, W_ih1, W_hh1, b_ih1, b_hh1,
                       W_ih2, W_hh2, b_ih2, b_hh2,
                       W_lin, b_lin, pred, out, T);
}